// Round 1
// baseline (229.505 us; speedup 1.0000x reference)
//
#include <hip/hip_runtime.h>

// BlockSample R7: all-192-channel blocks -> fully linear 12KB-per-pixel writes.
//
// R6 state: dur_us 225.9 = ~137us harness poison fill (runs at 6.7 TB/s, proves
// HBM write ceiling) + ~85us kernel (226.5MB writes at only ~3 TB/s effective).
// R6 block owned 16/192 channels -> per-wave store stream was a 1KB-chunk comb
// at 12KB stride. This version: block = (b, y, 24-px x-chunk) with ALL 192
// channels staged in 101KB dynamic LDS -> per pixel the block's 12 waves write
// the full 12KB contiguously (thread t <-> float4 slot t), 288KB linear sweep
// per task. Persistent 256 blocks (1/CU exactly), 3 tasks each, T14 reg-staged
// prefetch (next task's global loads issued before the store phase). b == XCD
// -> 1.77MB input slice L2-resident per XCD.
// Pitch 33: store-phase LDS bank = (lane + px + 2) % 32 -> 2 lanes/bank = free.
// Prediction: kernel ~85 -> ~45us, dur_us ~226 -> ~185.

#define CC 192
#define HH 48
#define WW 48
#define PXB 24              // pixels per task (x-chunk)
#define PITCH 33            // 32 staged cols + 1 spare
#define TPB 768             // 12 waves; thread t <-> (ch = t>>2, i = t&3)
#define NBLK 256
#define LDS_BYTES (CC * 4 * PITCH * 4)   // 768 rows x 33 floats x 4B = 101376

typedef float vfloat4 __attribute__((ext_vector_type(4)));

__global__ __launch_bounds__(TPB) void
blocksample_kernel(const float* __restrict__ in, float* __restrict__ out) {
    extern __shared__ float lds[];
    const int t  = threadIdx.x;
    const int id = blockIdx.x;
    const int b  = id & 7;         // XCD-partitioned batch (id%8 round-robin)
    const int k  = id >> 3;        // 0..31 within XCD
    const int xh = k & 1;          // x-chunk, constant across this block's tasks
    const int y0 = k >> 1;         // task r: y = y0 + 16*r, r = 0..2

    // Fill decode (task-invariant): thread t loads float4 slot q4 of LDS rows
    // rc = (t>>3) + 96q, q = 0..7. LDS row rc holds (ch = rc>>2, i = rc&3):
    // input row y+i-3, global cols [24*xh-4, 24*xh+28).
    const int q4   = t & 7;
    const int irow = (t >> 3) & 3;
    const int ch0  = t >> 5;                   // channel = ch0 + 24q
    const int colg = PXB * xh - 4 + 4 * q4;    // global col of this float4
    const bool colok = (colg >= 0) & (colg <= WW - 4);   // whole f4 in/out
    const float* inb = in + (size_t)b * CC * HH * WW;

    vfloat4 stage[8];

#define LOADTASK(yy) do {                                                     \
        const int row  = (yy) + irow - 3;                                     \
        const bool ok  = (row >= 0) & colok;                                  \
        const int rowc = (row >= 0) ? row : 0;   /* clamp: always valid addr */\
        const int colc = colok ? colg : 0;                                    \
        const float* p = inb + ((size_t)(ch0 * HH + rowc)) * WW + colc;       \
        _Pragma("unroll")                                                     \
        for (int q = 0; q < 8; ++q) {                                         \
            stage[q] = *(const vfloat4*)(p + (size_t)q * 24 * HH * WW);       \
            if (!ok) stage[q] = (vfloat4)(0.0f);                              \
        }                                                                     \
    } while (0)

    LOADTASK(y0);                  // prologue: task 0 loads in flight

    const float* lrow = lds + (size_t)t * PITCH;      // store row (4c+i == t)
    const bool masked = (t & 3) == 3;                 // i==3 -> taps j=2,3 zero
    float* dst0 = lds + ((size_t)(t >> 3)) * PITCH + 4 * q4;

    int y = y0;
    for (int r = 0; r < 3; ++r) {
        // stage -> LDS (compiler waits vmcnt on stage use)
        #pragma unroll
        for (int q = 0; q < 8; ++q) {
            float* d = dst0 + (size_t)q * 96 * PITCH;
            d[0] = stage[q].x; d[1] = stage[q].y;
            d[2] = stage[q].z; d[3] = stage[q].w;
        }
        __syncthreads();

        if (r < 2) LOADTASK(y + 16);   // T14: issue next task's loads early

        // Store phase: pixel x = 24*xh + px. Thread t writes float4 slot t of
        // the pixel's 12KB block; 12 waves cover it contiguously; px sweep ->
        // 288KB linear. LDS col (px+2+j) <-> global col x+j-2 (j = 0..3).
        vfloat4* op = (vfloat4*)out
            + ((size_t)((b * HH + y) * WW + PXB * xh)) * (CC * 4) + t;
        #pragma unroll
        for (int px = 0; px < PXB; ++px) {
            const float* p = lrow + (px + 2);
            vfloat4 v;
            v.x = p[0]; v.y = p[1]; v.z = p[2]; v.w = p[3];
            if (masked) { v.z = 0.0f; v.w = 0.0f; }   // masked taps (3,2),(3,3)
            op[(size_t)px * (CC * 4)] = v;
        }
        __syncthreads();               // all LDS reads done before next overwrite
        y += 16;
    }
#undef LOADTASK
}

extern "C" void kernel_launch(void* const* d_in, const int* in_sizes, int n_in,
                              void* d_out, int out_size, void* d_ws, size_t ws_size,
                              hipStream_t stream) {
    static bool inited = false;
    if (!inited) {
        hipFuncSetAttribute(reinterpret_cast<const void*>(blocksample_kernel),
                            hipFuncAttributeMaxDynamicSharedMemorySize, LDS_BYTES);
        inited = true;
    }
    const float* in = (const float*)d_in[0];
    float* out = (float*)d_out;
    blocksample_kernel<<<dim3(NBLK), dim3(TPB), LDS_BYTES, stream>>>(in, out);
}